// Round 10
// baseline (668.160 us; speedup 1.0000x reference)
//
#include <hip/hip_runtime.h>

#define NN 100000
#define NE 1600000

// ---------------------------------------------------------------------------
// Workspace layout in 4-byte units (~296 MB total; round-5 tier-1 proved
// ws_size >= ~498 MB, so this fits)
// ---------------------------------------------------------------------------
#define OFF_M    0                         // 128*128 folded [A | wu1_top]
#define OFF_B    (OFF_M + 16384)           // 32*64   we @ wm1_bot
#define OFF_C    (OFF_B + 2048)            // 64      folded msg bias
#define OFF_W2U  (OFF_C + 64)              // 64*64   wm2 @ wu1_bot
#define OFF_D2   (OFF_W2U + 4096)          // 64      bm2 @ wu1_bot
#define OFF_BSUM (OFF_D2 + 64)             // 128 block sums (scan)
#define OFF_BOFF (OFF_BSUM + 128)          // 128 block offsets (scan)
#define OFF_PRA  (OFF_BOFF + 128)          // NN*64
#define OFF_PRU  (OFF_PRA + NN * 64)       // NN*64
#define OFF_H    (OFF_PRU + NN * 64)       // NN*64  (agg in fallback)
#define OFF_HIST (OFF_H + NN * 64)         // NN
#define OFF_CUR  (OFF_HIST + NN)           // NN
#define OFF_STRT (OFF_CUR + NN)            // NN+1 (+pad)
#define OFF_SLOT (OFF_STRT + NN + 4)       // NE: slotOf[e]
#define OFF_SRCS (OFF_SLOT + NE)           // NE: src sorted by dst
#define OFF_QS   (OFF_SRCS + NE)           // NE*64 bf16 = NE*32 dwords
#define WS_UNITS (OFF_QS + NE * 32)

__device__ __forceinline__ unsigned bfr(float x) {
  unsigned u = __float_as_uint(x);
  return (u + 0x7fffu + ((u >> 16) & 1u)) >> 16;
}
__device__ __forceinline__ float bf2f(unsigned short h) {
  return __uint_as_float(((unsigned)h) << 16);
}

// ---------------------------------------------------------------------------
// Weight folding:
//   M[128][128]: cols 0-63 = wn@wm1_top ; cols 64-127 = wu1[0:128,:]
//   B[32][64] = we@wm1_bot ; c = bm1 + bn@wm1_top + be@wm1_bot
//   W2U[64][64] = wm2 @ wu1_bot ; d2 = bm2 @ wu1_bot
// ---------------------------------------------------------------------------
__global__ __launch_bounds__(256) void k_fold(
    const float* __restrict__ wn, const float* __restrict__ bn,
    const float* __restrict__ we, const float* __restrict__ be,
    const float* __restrict__ wm1, const float* __restrict__ bm1,
    const float* __restrict__ wm2, const float* __restrict__ bm2,
    const float* __restrict__ wu1,
    float* __restrict__ M, float* __restrict__ B, float* __restrict__ c,
    float* __restrict__ W2U, float* __restrict__ d2) {
  int t = blockIdx.x * 256 + threadIdx.x;
  if (t < 16384) {
    int k = t >> 7, j = t & 127;
    float acc;
    if (j < 64) {
      acc = 0.f;
      for (int h = 0; h < 64; ++h) acc += wn[k * 64 + h] * wm1[h * 64 + j];
    } else {
      acc = wu1[k * 64 + (j - 64)];
    }
    M[t] = acc;
  } else if (t < 16384 + 2048) {
    int u = t - 16384;
    int k = u >> 6, j = u & 63;
    float acc = 0.f;
    for (int h = 0; h < 64; ++h) acc += we[k * 64 + h] * wm1[(64 + h) * 64 + j];
    B[u] = acc;
  } else if (t < 16384 + 2048 + 64) {
    int j = t - (16384 + 2048);
    float acc = bm1[j];
    for (int h = 0; h < 64; ++h)
      acc += bn[h] * wm1[h * 64 + j] + be[h] * wm1[(64 + h) * 64 + j];
    c[j] = acc;
  } else if (t < 16384 + 2048 + 64 + 4096) {
    int u = t - (16384 + 2048 + 64);
    int k = u >> 6, j = u & 63;
    float acc = 0.f;
    for (int h = 0; h < 64; ++h) acc += wm2[k * 64 + h] * wu1[(128 + h) * 64 + j];
    W2U[u] = acc;
  } else if (t < 16384 + 2048 + 64 + 4096 + 64) {
    int j = t - (16384 + 2048 + 64 + 4096);
    float acc = 0.f;
    for (int h = 0; h < 64; ++h) acc += bm2[h] * wu1[(128 + h) * 64 + j];
    d2[j] = acc;
  }
}

// ---------------------------------------------------------------------------
// PRA[n] = nf[n]@A ; PRU[n] = nf[n]@wu1_top  (lane-per-node, scalar weights)
// ---------------------------------------------------------------------------
__global__ __launch_bounds__(256) void k_node(
    const float* __restrict__ nf, const float* __restrict__ M,
    float* __restrict__ PRA, float* __restrict__ PRU) {
  int n = blockIdx.x * 256 + threadIdx.x;
  if (n >= NN) return;
  const float* __restrict__ row = &nf[(size_t)n * 128];
#pragma unroll 1
  for (int jc = 0; jc < 128; jc += 32) {
    float q[32];
#pragma unroll
    for (int jj = 0; jj < 32; ++jj) q[jj] = 0.f;
#pragma unroll 4
    for (int k = 0; k < 128; k += 4) {
      float4 r4 = *(const float4*)&row[k];
#pragma unroll
      for (int jj = 0; jj < 32; ++jj) q[jj] += r4.x * M[(k + 0) * 128 + jc + jj];
#pragma unroll
      for (int jj = 0; jj < 32; ++jj) q[jj] += r4.y * M[(k + 1) * 128 + jc + jj];
#pragma unroll
      for (int jj = 0; jj < 32; ++jj) q[jj] += r4.z * M[(k + 2) * 128 + jc + jj];
#pragma unroll
      for (int jj = 0; jj < 32; ++jj) q[jj] += r4.w * M[(k + 3) * 128 + jc + jj];
    }
    float* dstp = (jc < 64) ? &PRA[(size_t)n * 64 + jc] : &PRU[(size_t)n * 64 + (jc - 64)];
#pragma unroll
    for (int jj = 0; jj < 32; jj += 4)
      *(float4*)&dstp[jj] = make_float4(q[jj], q[jj + 1], q[jj + 2], q[jj + 3]);
  }
}

// ---------------------------------------------------------------------------
// Counting sort: hist -> 3-phase scan -> scatter
// ---------------------------------------------------------------------------
__global__ __launch_bounds__(256) void k_hist(const int* __restrict__ idx,
                                              int* __restrict__ hist) {
  int e = blockIdx.x * 256 + threadIdx.x;
  if (e < NE) atomicAdd(&hist[idx[NE + e]], 1);
}

__global__ __launch_bounds__(1024) void k_scanA(const int* __restrict__ hist,
                                                int* __restrict__ strt,
                                                int* __restrict__ bsum) {
  __shared__ int lds[1024];
  int t = threadIdx.x;
  int i = blockIdx.x * 1024 + t;
  int v = (i < NN) ? hist[i] : 0;
  lds[t] = v;
  __syncthreads();
  for (int off = 1; off < 1024; off <<= 1) {
    int u = (t >= off) ? lds[t - off] : 0;
    __syncthreads();
    lds[t] += u;
    __syncthreads();
  }
  if (i < NN) strt[i] = lds[t] - v;
  if (t == 1023) bsum[blockIdx.x] = lds[1023];
}

__global__ __launch_bounds__(128) void k_scanB(const int* __restrict__ bsum,
                                               int* __restrict__ boff,
                                               int* __restrict__ strt,
                                               int nblocks) {
  __shared__ int lds[128];
  int t = threadIdx.x;
  int v = (t < nblocks) ? bsum[t] : 0;
  lds[t] = v;
  __syncthreads();
  for (int off = 1; off < 128; off <<= 1) {
    int u = (t >= off) ? lds[t - off] : 0;
    __syncthreads();
    lds[t] += u;
    __syncthreads();
  }
  if (t < nblocks) boff[t] = lds[t] - v;
  if (t == 127) strt[NN] = lds[127];
}

__global__ __launch_bounds__(1024) void k_scanC(int* __restrict__ strt,
                                                const int* __restrict__ boff) {
  int i = blockIdx.x * 1024 + threadIdx.x;
  if (i < NN) strt[i] += boff[blockIdx.x];
}

// slotOf[e] (coalesced) + srcS[slot] (scattered 4B)
__global__ __launch_bounds__(256) void k_scatter_slot2(
    const int* __restrict__ idx, const int* __restrict__ strt,
    int* __restrict__ cursor, int* __restrict__ slotOf,
    int* __restrict__ srcS) {
  int e = blockIdx.x * 256 + threadIdx.x;
  if (e >= NE) return;
  int dst = idx[NE + e];
  int pos = atomicAdd(&cursor[dst], 1);
  int slot = strt[dst] + pos;
  slotOf[e] = slot;
  srcS[slot] = idx[e];
}

// ---------------------------------------------------------------------------
// k_msgq: lane-per-edge in EDGE order (streaming ef, scalar-loaded B),
// q = ef@B + c -> bf16, scatter-store 128B row to dst-sorted slot.
// No broadcast needed in this geometry; no PRA access here.
// ---------------------------------------------------------------------------
__global__ __launch_bounds__(256) void k_msgq(
    const int* __restrict__ slotOf, const float* __restrict__ ef,
    const float* __restrict__ Bm, const float* __restrict__ c,
    unsigned short* __restrict__ qS) {
  int e = blockIdx.x * 256 + threadIdx.x;
  if (e >= NE) return;
  int slot = slotOf[e];
  float efr[32];
#pragma unroll
  for (int k = 0; k < 32; k += 4)
    *(float4*)&efr[k] = *(const float4*)&ef[(size_t)e * 32 + k];
  unsigned* __restrict__ qp = (unsigned*)(qS + (size_t)slot * 64);
#pragma unroll 1
  for (int jc = 0; jc < 64; jc += 16) {
    float q[16];
#pragma unroll
    for (int jj = 0; jj < 16; ++jj) q[jj] = c[jc + jj];
#pragma unroll
    for (int k = 0; k < 32; ++k) {
      float ev = efr[k];
#pragma unroll
      for (int jj = 0; jj < 16; ++jj) q[jj] += ev * Bm[k * 64 + jc + jj];
    }
    unsigned w[8];
#pragma unroll
    for (int p = 0; p < 8; ++p)
      w[p] = bfr(q[2 * p]) | (bfr(q[2 * p + 1]) << 16);
    *(uint4*)&qp[jc / 2] = make_uint4(w[0], w[1], w[2], w[3]);
    *(uint4*)&qp[jc / 2 + 4] = make_uint4(w[4], w[5], w[6], w[7]);
  }
}

// ---------------------------------------------------------------------------
// k_gather7: wave-per-node, lane = dim. Per edge: acc += relu(PRA[src]+q).
// qS read is sequential/coalesced (sorted); only PRA is a random row (L3-hot).
// Depth-2 register pipeline; src indices prefetched one step further.
// Clamped indices -> no branches in the refill path.
// ---------------------------------------------------------------------------
__global__ __launch_bounds__(256) void k_gather7(
    const int* __restrict__ srcS, const unsigned short* __restrict__ qS,
    const int* __restrict__ strt, const float* __restrict__ PRA,
    float* __restrict__ H) {
  int wib = threadIdx.x >> 6;
  int lane = threadIdx.x & 63;
  int n = blockIdx.x * 4 + wib;
  if (n >= NN) return;
  int s0 = strt[n], s1 = strt[n + 1];
  float acc = 0.f;
  if (s0 < s1) {
    int last = s1 - 1;
    int srcA = srcS[s0];
    int srcB = srcS[min(s0 + 1, last)];
    int srcC = srcS[min(s0 + 2, last)];
    int srcD = srcS[min(s0 + 3, last)];
    float prA = PRA[(size_t)srcA * 64 + lane];
    float prB = PRA[(size_t)srcB * 64 + lane];
    unsigned short qA = qS[(size_t)s0 * 64 + lane];
    unsigned short qB = qS[(size_t)min(s0 + 1, last) * 64 + lane];
    int s = s0;
#pragma unroll 1
    while (s + 1 < s1) {
      // compute edge s (A); refill A <- edge s+2 (src already prefetched)
      float pr = prA;
      float qv = bf2f(qA);
      prA = PRA[(size_t)srcC * 64 + lane];
      qA = qS[(size_t)min(s + 2, last) * 64 + lane];
      srcC = srcS[min(s + 4, last)];
      acc += fmaxf(pr + qv, 0.f);
      // compute edge s+1 (B); refill B <- edge s+3
      pr = prB;
      qv = bf2f(qB);
      prB = PRA[(size_t)srcD * 64 + lane];
      qB = qS[(size_t)min(s + 3, last) * 64 + lane];
      srcD = srcS[min(s + 5, last)];
      acc += fmaxf(pr + qv, 0.f);
      s += 2;
    }
    if (s < s1) acc += fmaxf(prA + bf2f(qA), 0.f);
  }
  H[(size_t)n * 64 + lane] = acc;
}

// ---------------------------------------------------------------------------
// Final per-node MLP with W2U fold:
//   pre = PRU[n] + H[n]@W2U + deg*d2 + bu1 ; out = relu(pre)@wu2 + bu2
// ---------------------------------------------------------------------------
__global__ __launch_bounds__(256) void k_update3(
    const float* __restrict__ H, const int* __restrict__ strt,
    const float* __restrict__ PRU,
    const float* __restrict__ W2U, const float* __restrict__ d2,
    const float* __restrict__ bu1,
    const float* __restrict__ wu2, const float* __restrict__ bu2,
    float* __restrict__ out) {
  int n = blockIdx.x * 256 + threadIdx.x;
  if (n >= NN) return;

  float Hr[64];
#pragma unroll
  for (int k = 0; k < 64; k += 4)
    *(float4*)&Hr[k] = *(const float4*)&H[(size_t)n * 64 + k];
  float deg = (float)(strt[n + 1] - strt[n]);

  float acc[64];
#pragma unroll
  for (int o = 0; o < 64; ++o) acc[o] = bu2[o];

  const float* __restrict__ prs = &PRU[(size_t)n * 64];
#pragma unroll 1
  for (int jc = 0; jc < 64; jc += 16) {
    float q[16];
#pragma unroll
    for (int jj = 0; jj < 16; ++jj) q[jj] = bu1[jc + jj] + deg * d2[jc + jj];
#pragma unroll
    for (int k = 0; k < 64; ++k) {
      float hv = Hr[k];
#pragma unroll
      for (int jj = 0; jj < 16; ++jj) q[jj] += hv * W2U[k * 64 + jc + jj];
    }
#pragma unroll
    for (int jj = 0; jj < 16; ++jj) {
      float h = fmaxf(prs[jc + jj] + q[jj], 0.f);
#pragma unroll
      for (int o = 0; o < 64; ++o) acc[o] += h * wu2[(jc + jj) * 64 + o];
    }
  }

#pragma unroll
  for (int o = 0; o < 64; o += 4)
    *(float4*)&out[(size_t)n * 64 + o] = make_float4(acc[o], acc[o + 1], acc[o + 2], acc[o + 3]);
}

// ---------------------------------------------------------------------------
// Fallback (ws too small): round-1 atomic scatter path
// ---------------------------------------------------------------------------
__global__ __launch_bounds__(256) void k_edge_at(
    const int* __restrict__ idx, const float* __restrict__ ef,
    const float* __restrict__ B, const float* __restrict__ c,
    const float* __restrict__ wm2, const float* __restrict__ bm2,
    const float* __restrict__ PRA, float* __restrict__ agg) {
  int e = blockIdx.x * 256 + threadIdx.x;
  if (e >= NE) return;
  int src = idx[e];
  int dst = idx[NE + e];
  float efr[32];
#pragma unroll
  for (int k = 0; k < 32; k += 4)
    *(float4*)&efr[k] = *(const float4*)&ef[(size_t)e * 32 + k];
  float m[64];
#pragma unroll
  for (int o = 0; o < 64; ++o) m[o] = bm2[o];
  const float* __restrict__ prs = &PRA[(size_t)src * 64];
#pragma unroll 1
  for (int jc = 0; jc < 64; jc += 16) {
    float q[16];
#pragma unroll
    for (int jj = 0; jj < 16; ++jj) q[jj] = c[jc + jj];
#pragma unroll
    for (int k = 0; k < 32; ++k) {
      float ev = efr[k];
#pragma unroll
      for (int jj = 0; jj < 16; ++jj) q[jj] += ev * B[k * 64 + jc + jj];
    }
#pragma unroll
    for (int jj = 0; jj < 16; ++jj) {
      float h = fmaxf(prs[jc + jj] + q[jj], 0.f);
#pragma unroll
      for (int o = 0; o < 64; ++o) m[o] += h * wm2[(jc + jj) * 64 + o];
    }
  }
  float* __restrict__ ap = &agg[(size_t)dst * 64];
#pragma unroll
  for (int o = 0; o < 64; ++o) atomicAdd(&ap[o], m[o]);
}

__global__ __launch_bounds__(256) void k_update_at(
    const float* __restrict__ agg, const float* __restrict__ PRU,
    const float* __restrict__ wu1, const float* __restrict__ bu1,
    const float* __restrict__ wu2, const float* __restrict__ bu2,
    float* __restrict__ out) {
  int n = blockIdx.x * 256 + threadIdx.x;
  if (n >= NN) return;
  float ar[64];
#pragma unroll
  for (int k = 0; k < 64; k += 4)
    *(float4*)&ar[k] = *(const float4*)&agg[(size_t)n * 64 + k];
  float acc[64];
#pragma unroll
  for (int o = 0; o < 64; ++o) acc[o] = bu2[o];
  const float* __restrict__ prs = &PRU[(size_t)n * 64];
#pragma unroll 1
  for (int jc = 0; jc < 64; jc += 16) {
    float q[16];
#pragma unroll
    for (int jj = 0; jj < 16; ++jj) q[jj] = bu1[jc + jj];
#pragma unroll
    for (int k = 0; k < 64; ++k) {
      float av = ar[k];
#pragma unroll
      for (int jj = 0; jj < 16; ++jj) q[jj] += av * wu1[(128 + k) * 64 + jc + jj];
    }
#pragma unroll
    for (int jj = 0; jj < 16; ++jj) {
      float h = fmaxf(prs[jc + jj] + q[jj], 0.f);
#pragma unroll
      for (int o = 0; o < 64; ++o) acc[o] += h * wu2[(jc + jj) * 64 + o];
    }
  }
#pragma unroll
  for (int o = 0; o < 64; o += 4)
    *(float4*)&out[(size_t)n * 64 + o] = make_float4(acc[o], acc[o + 1], acc[o + 2], acc[o + 3]);
}

extern "C" void kernel_launch(void* const* d_in, const int* in_sizes, int n_in,
                              void* d_out, int out_size, void* d_ws, size_t ws_size,
                              hipStream_t stream) {
  const float* nf  = (const float*)d_in[0];
  const int*   idx = (const int*)d_in[1];
  const float* ef  = (const float*)d_in[2];
  const float* wn  = (const float*)d_in[3];
  const float* bn  = (const float*)d_in[4];
  const float* we  = (const float*)d_in[5];
  const float* be  = (const float*)d_in[6];
  const float* wm1 = (const float*)d_in[7];
  const float* bm1 = (const float*)d_in[8];
  const float* wm2 = (const float*)d_in[9];
  const float* bm2 = (const float*)d_in[10];
  const float* wu1 = (const float*)d_in[11];
  const float* bu1 = (const float*)d_in[12];
  const float* wu2 = (const float*)d_in[13];
  const float* bu2 = (const float*)d_in[14];
  float* out = (float*)d_out;

  float* ws   = (float*)d_ws;
  float* M    = ws + OFF_M;
  float* B    = ws + OFF_B;
  float* c    = ws + OFF_C;
  float* W2U  = ws + OFF_W2U;
  float* d2   = ws + OFF_D2;
  int*   bsum = (int*)(ws + OFF_BSUM);
  int*   boff = (int*)(ws + OFF_BOFF);
  float* PRA  = ws + OFF_PRA;
  float* PRU  = ws + OFF_PRU;
  float* H    = ws + OFF_H;
  int*   hist = (int*)(ws + OFF_HIST);
  int*   cur  = (int*)(ws + OFF_CUR);
  int*   strt = (int*)(ws + OFF_STRT);
  int*   slot = (int*)(ws + OFF_SLOT);
  int*   srcS = (int*)(ws + OFF_SRCS);
  unsigned short* qS = (unsigned short*)(ws + OFF_QS);

  const int SCAN_BLOCKS = (NN + 1023) / 1024;  // 98

  k_fold<<<(16384 + 2048 + 64 + 4096 + 64 + 255) / 256, 256, 0, stream>>>(
      wn, bn, we, be, wm1, bm1, wm2, bm2, wu1, M, B, c, W2U, d2);
  k_node<<<(NN + 255) / 256, 256, 0, stream>>>(nf, M, PRA, PRU);

  if (ws_size >= (size_t)WS_UNITS * 4) {
    hipMemsetAsync(hist, 0, (size_t)2 * NN * sizeof(int), stream);
    k_hist<<<(NE + 255) / 256, 256, 0, stream>>>(idx, hist);
    k_scanA<<<SCAN_BLOCKS, 1024, 0, stream>>>(hist, strt, bsum);
    k_scanB<<<1, 128, 0, stream>>>(bsum, boff, strt, SCAN_BLOCKS);
    k_scanC<<<SCAN_BLOCKS, 1024, 0, stream>>>(strt, boff);
    k_scatter_slot2<<<(NE + 255) / 256, 256, 0, stream>>>(idx, strt, cur, slot, srcS);
    k_msgq<<<(NE + 255) / 256, 256, 0, stream>>>(slot, ef, B, c, qS);
    k_gather7<<<(NN + 3) / 4, 256, 0, stream>>>(srcS, qS, strt, PRA, H);
    k_update3<<<(NN + 255) / 256, 256, 0, stream>>>(
        H, strt, PRU, W2U, d2, bu1, wu2, bu2, out);
  } else {
    hipMemsetAsync(H, 0, (size_t)NN * 64 * sizeof(float), stream);
    k_edge_at<<<(NE + 255) / 256, 256, 0, stream>>>(idx, ef, B, c, wm2, bm2, PRA, H);
    k_update_at<<<(NN + 255) / 256, 256, 0, stream>>>(
        H, PRU, wu1, bu1, wu2, bu2, out);
  }
}

// Round 11
// 555.621 us; speedup vs baseline: 1.2025x; 1.2025x over previous
//
#include <hip/hip_runtime.h>

#define NN 100000
#define NE 1600000

// ---------------------------------------------------------------------------
// Workspace layout in 4-byte units (~290 MB total; round-5 tier-1 proved
// ws_size >= ~494 MB, so this fits)
// ---------------------------------------------------------------------------
#define OFF_M    0                         // 128*128 folded [A | wu1_top]
#define OFF_B    (OFF_M + 16384)           // 32*64   we @ wm1_bot
#define OFF_C    (OFF_B + 2048)            // 64      folded msg bias
#define OFF_W2U  (OFF_C + 64)              // 64*64   wm2 @ wu1_bot
#define OFF_D2   (OFF_W2U + 4096)          // 64      bm2 @ wu1_bot
#define OFF_BSUM (OFF_D2 + 64)             // 128 block sums (scan)
#define OFF_BOFF (OFF_BSUM + 128)          // 128 block offsets (scan)
#define OFF_PRA  (OFF_BOFF + 128)          // NN*64
#define OFF_PRU  (OFF_PRA + NN * 64)       // NN*64
#define OFF_H    (OFF_PRU + NN * 64)       // NN*64  (agg in fallback)
#define OFF_HIST (OFF_H + NN * 64)         // NN
#define OFF_CUR  (OFF_HIST + NN)           // NN
#define OFF_STRT (OFF_CUR + NN)            // NN+1 (+pad)
#define OFF_SRCS (OFF_STRT + NN + 4)       // NE: src sorted by dst
#define OFF_QS   (OFF_SRCS + NE)           // NE*64 bf16 = NE*32 dwords
#define WS_UNITS (OFF_QS + NE * 32)

__device__ __forceinline__ unsigned bfr(float x) {
  unsigned u = __float_as_uint(x);
  return (u + 0x7fffu + ((u >> 16) & 1u)) >> 16;
}
__device__ __forceinline__ float bf2f(unsigned short h) {
  return __uint_as_float(((unsigned)h) << 16);
}

// ---------------------------------------------------------------------------
// Weight folding:
//   M[128][128]: cols 0-63 = wn@wm1_top ; cols 64-127 = wu1[0:128,:]
//   B[32][64] = we@wm1_bot ; c = bm1 + bn@wm1_top + be@wm1_bot
//   W2U[64][64] = wm2 @ wu1_bot ; d2 = bm2 @ wu1_bot
// ---------------------------------------------------------------------------
__global__ __launch_bounds__(256) void k_fold(
    const float* __restrict__ wn, const float* __restrict__ bn,
    const float* __restrict__ we, const float* __restrict__ be,
    const float* __restrict__ wm1, const float* __restrict__ bm1,
    const float* __restrict__ wm2, const float* __restrict__ bm2,
    const float* __restrict__ wu1,
    float* __restrict__ M, float* __restrict__ B, float* __restrict__ c,
    float* __restrict__ W2U, float* __restrict__ d2) {
  int t = blockIdx.x * 256 + threadIdx.x;
  if (t < 16384) {
    int k = t >> 7, j = t & 127;
    float acc;
    if (j < 64) {
      acc = 0.f;
      for (int h = 0; h < 64; ++h) acc += wn[k * 64 + h] * wm1[h * 64 + j];
    } else {
      acc = wu1[k * 64 + (j - 64)];
    }
    M[t] = acc;
  } else if (t < 16384 + 2048) {
    int u = t - 16384;
    int k = u >> 6, j = u & 63;
    float acc = 0.f;
    for (int h = 0; h < 64; ++h) acc += we[k * 64 + h] * wm1[(64 + h) * 64 + j];
    B[u] = acc;
  } else if (t < 16384 + 2048 + 64) {
    int j = t - (16384 + 2048);
    float acc = bm1[j];
    for (int h = 0; h < 64; ++h)
      acc += bn[h] * wm1[h * 64 + j] + be[h] * wm1[(64 + h) * 64 + j];
    c[j] = acc;
  } else if (t < 16384 + 2048 + 64 + 4096) {
    int u = t - (16384 + 2048 + 64);
    int k = u >> 6, j = u & 63;
    float acc = 0.f;
    for (int h = 0; h < 64; ++h) acc += wm2[k * 64 + h] * wu1[(128 + h) * 64 + j];
    W2U[u] = acc;
  } else if (t < 16384 + 2048 + 64 + 4096 + 64) {
    int j = t - (16384 + 2048 + 64 + 4096);
    float acc = 0.f;
    for (int h = 0; h < 64; ++h) acc += bm2[h] * wu1[(128 + h) * 64 + j];
    d2[j] = acc;
  }
}

// ---------------------------------------------------------------------------
// PRA[n] = nf[n]@A ; PRU[n] = nf[n]@wu1_top  (lane-per-node, scalar weights)
// ---------------------------------------------------------------------------
__global__ __launch_bounds__(256) void k_node(
    const float* __restrict__ nf, const float* __restrict__ M,
    float* __restrict__ PRA, float* __restrict__ PRU) {
  int n = blockIdx.x * 256 + threadIdx.x;
  if (n >= NN) return;
  const float* __restrict__ row = &nf[(size_t)n * 128];
#pragma unroll 1
  for (int jc = 0; jc < 128; jc += 32) {
    float q[32];
#pragma unroll
    for (int jj = 0; jj < 32; ++jj) q[jj] = 0.f;
#pragma unroll 4
    for (int k = 0; k < 128; k += 4) {
      float4 r4 = *(const float4*)&row[k];
#pragma unroll
      for (int jj = 0; jj < 32; ++jj) q[jj] += r4.x * M[(k + 0) * 128 + jc + jj];
#pragma unroll
      for (int jj = 0; jj < 32; ++jj) q[jj] += r4.y * M[(k + 1) * 128 + jc + jj];
#pragma unroll
      for (int jj = 0; jj < 32; ++jj) q[jj] += r4.z * M[(k + 2) * 128 + jc + jj];
#pragma unroll
      for (int jj = 0; jj < 32; ++jj) q[jj] += r4.w * M[(k + 3) * 128 + jc + jj];
    }
    float* dstp = (jc < 64) ? &PRA[(size_t)n * 64 + jc] : &PRU[(size_t)n * 64 + (jc - 64)];
#pragma unroll
    for (int jj = 0; jj < 32; jj += 4)
      *(float4*)&dstp[jj] = make_float4(q[jj], q[jj + 1], q[jj + 2], q[jj + 3]);
  }
}

// ---------------------------------------------------------------------------
// Counting sort: hist -> 3-phase scan
// ---------------------------------------------------------------------------
__global__ __launch_bounds__(256) void k_hist(const int* __restrict__ idx,
                                              int* __restrict__ hist) {
  int e = blockIdx.x * 256 + threadIdx.x;
  if (e < NE) atomicAdd(&hist[idx[NE + e]], 1);
}

__global__ __launch_bounds__(1024) void k_scanA(const int* __restrict__ hist,
                                                int* __restrict__ strt,
                                                int* __restrict__ bsum) {
  __shared__ int lds[1024];
  int t = threadIdx.x;
  int i = blockIdx.x * 1024 + t;
  int v = (i < NN) ? hist[i] : 0;
  lds[t] = v;
  __syncthreads();
  for (int off = 1; off < 1024; off <<= 1) {
    int u = (t >= off) ? lds[t - off] : 0;
    __syncthreads();
    lds[t] += u;
    __syncthreads();
  }
  if (i < NN) strt[i] = lds[t] - v;
  if (t == 1023) bsum[blockIdx.x] = lds[1023];
}

__global__ __launch_bounds__(128) void k_scanB(const int* __restrict__ bsum,
                                               int* __restrict__ boff,
                                               int* __restrict__ strt,
                                               int nblocks) {
  __shared__ int lds[128];
  int t = threadIdx.x;
  int v = (t < nblocks) ? bsum[t] : 0;
  lds[t] = v;
  __syncthreads();
  for (int off = 1; off < 128; off <<= 1) {
    int u = (t >= off) ? lds[t - off] : 0;
    __syncthreads();
    lds[t] += u;
    __syncthreads();
  }
  if (t < nblocks) boff[t] = lds[t] - v;
  if (t == 127) strt[NN] = lds[127];
}

__global__ __launch_bounds__(1024) void k_scanC(int* __restrict__ strt,
                                                const int* __restrict__ boff) {
  int i = blockIdx.x * 1024 + threadIdx.x;
  if (i < NN) strt[i] += boff[blockIdx.x];
}

// ---------------------------------------------------------------------------
// k_msgq2: lane-per-edge in EDGE order. Computes dst-sorted slot (atomic
// cursor), srcS[slot], and q = ef@B + c -> bf16, buffered fully in registers
// and stored as ONE 128B burst (8 consecutive uint4) -> single dirty line.
// ---------------------------------------------------------------------------
__global__ __launch_bounds__(256) void k_msgq2(
    const int* __restrict__ idx, const int* __restrict__ strt,
    int* __restrict__ cursor, const float* __restrict__ ef,
    const float* __restrict__ Bm, const float* __restrict__ c,
    int* __restrict__ srcS, unsigned short* __restrict__ qS) {
  int e = blockIdx.x * 256 + threadIdx.x;
  if (e >= NE) return;
  int src = idx[e];
  int dst = idx[NE + e];
  int pos = atomicAdd(&cursor[dst], 1);
  int slot = strt[dst] + pos;
  srcS[slot] = src;

  float efr[32];
#pragma unroll
  for (int k = 0; k < 32; k += 4)
    *(float4*)&efr[k] = *(const float4*)&ef[(size_t)e * 32 + k];

  unsigned w[32];
#pragma unroll 1
  for (int jc = 0; jc < 64; jc += 16) {
    float q[16];
#pragma unroll
    for (int jj = 0; jj < 16; ++jj) q[jj] = c[jc + jj];
#pragma unroll
    for (int k = 0; k < 32; ++k) {
      float ev = efr[k];
#pragma unroll
      for (int jj = 0; jj < 16; ++jj) q[jj] += ev * Bm[k * 64 + jc + jj];
    }
#pragma unroll
    for (int p = 0; p < 8; ++p)
      w[jc / 2 + p] = bfr(q[2 * p]) | (bfr(q[2 * p + 1]) << 16);
  }

  uint4* __restrict__ qp = (uint4*)(qS + (size_t)slot * 64);
#pragma unroll
  for (int u = 0; u < 8; ++u)
    qp[u] = make_uint4(w[4 * u], w[4 * u + 1], w[4 * u + 2], w[4 * u + 3]);
}

// ---------------------------------------------------------------------------
// k_gather7 (depth-4): wave-per-node, lane = dim.
// Per edge: acc += relu(PRA[src] + q). qS sequential (sorted); PRA random
// row but L3-resident. 4 in-flight edge streams, branchless clamped refills,
// src indices prefetched 8 ahead.
// ---------------------------------------------------------------------------
__global__ __launch_bounds__(256) void k_gather7(
    const int* __restrict__ srcS, const unsigned short* __restrict__ qS,
    const int* __restrict__ strt, const float* __restrict__ PRA,
    float* __restrict__ H) {
  int wib = threadIdx.x >> 6;
  int lane = threadIdx.x & 63;
  int n = blockIdx.x * 4 + wib;
  if (n >= NN) return;
  int s0 = strt[n], s1 = strt[n + 1];
  float acc = 0.f;
  if (s0 < s1) {
    int last = s1 - 1;
#define CL(i) min((i), last)
    int srcA = srcS[s0];
    int srcB = srcS[CL(s0 + 1)];
    int srcC = srcS[CL(s0 + 2)];
    int srcD = srcS[CL(s0 + 3)];
    float prA = PRA[(size_t)srcA * 64 + lane];
    float prB = PRA[(size_t)srcB * 64 + lane];
    float prC = PRA[(size_t)srcC * 64 + lane];
    float prD = PRA[(size_t)srcD * 64 + lane];
    unsigned short qA = qS[(size_t)s0 * 64 + lane];
    unsigned short qB = qS[(size_t)CL(s0 + 1) * 64 + lane];
    unsigned short qC = qS[(size_t)CL(s0 + 2) * 64 + lane];
    unsigned short qD = qS[(size_t)CL(s0 + 3) * 64 + lane];
    int srcE = srcS[CL(s0 + 4)];
    int srcF = srcS[CL(s0 + 5)];
    int srcG = srcS[CL(s0 + 6)];
    int srcH = srcS[CL(s0 + 7)];
    int s = s0;
#pragma unroll 1
    while (s + 3 < s1) {
      float a0 = fmaxf(prA + bf2f(qA), 0.f);
      prA = PRA[(size_t)srcE * 64 + lane];
      qA = qS[(size_t)CL(s + 4) * 64 + lane];
      srcE = srcS[CL(s + 8)];
      float a1 = fmaxf(prB + bf2f(qB), 0.f);
      prB = PRA[(size_t)srcF * 64 + lane];
      qB = qS[(size_t)CL(s + 5) * 64 + lane];
      srcF = srcS[CL(s + 9)];
      float a2 = fmaxf(prC + bf2f(qC), 0.f);
      prC = PRA[(size_t)srcG * 64 + lane];
      qC = qS[(size_t)CL(s + 6) * 64 + lane];
      srcG = srcS[CL(s + 10)];
      float a3 = fmaxf(prD + bf2f(qD), 0.f);
      prD = PRA[(size_t)srcH * 64 + lane];
      qD = qS[(size_t)CL(s + 7) * 64 + lane];
      srcH = srcS[CL(s + 11)];
      acc += (a0 + a1) + (a2 + a3);
      s += 4;
    }
    int rem = s1 - s;
    if (rem > 0) acc += fmaxf(prA + bf2f(qA), 0.f);
    if (rem > 1) acc += fmaxf(prB + bf2f(qB), 0.f);
    if (rem > 2) acc += fmaxf(prC + bf2f(qC), 0.f);
#undef CL
  }
  H[(size_t)n * 64 + lane] = acc;
}

// ---------------------------------------------------------------------------
// Final per-node MLP with W2U fold:
//   pre = PRU[n] + H[n]@W2U + deg*d2 + bu1 ; out = relu(pre)@wu2 + bu2
// ---------------------------------------------------------------------------
__global__ __launch_bounds__(256) void k_update3(
    const float* __restrict__ H, const int* __restrict__ strt,
    const float* __restrict__ PRU,
    const float* __restrict__ W2U, const float* __restrict__ d2,
    const float* __restrict__ bu1,
    const float* __restrict__ wu2, const float* __restrict__ bu2,
    float* __restrict__ out) {
  int n = blockIdx.x * 256 + threadIdx.x;
  if (n >= NN) return;

  float Hr[64];
#pragma unroll
  for (int k = 0; k < 64; k += 4)
    *(float4*)&Hr[k] = *(const float4*)&H[(size_t)n * 64 + k];
  float deg = (float)(strt[n + 1] - strt[n]);

  float acc[64];
#pragma unroll
  for (int o = 0; o < 64; ++o) acc[o] = bu2[o];

  const float* __restrict__ prs = &PRU[(size_t)n * 64];
#pragma unroll 1
  for (int jc = 0; jc < 64; jc += 16) {
    float q[16];
#pragma unroll
    for (int jj = 0; jj < 16; ++jj) q[jj] = bu1[jc + jj] + deg * d2[jc + jj];
#pragma unroll
    for (int k = 0; k < 64; ++k) {
      float hv = Hr[k];
#pragma unroll
      for (int jj = 0; jj < 16; ++jj) q[jj] += hv * W2U[k * 64 + jc + jj];
    }
#pragma unroll
    for (int jj = 0; jj < 16; ++jj) {
      float h = fmaxf(prs[jc + jj] + q[jj], 0.f);
#pragma unroll
      for (int o = 0; o < 64; ++o) acc[o] += h * wu2[(jc + jj) * 64 + o];
    }
  }

#pragma unroll
  for (int o = 0; o < 64; o += 4)
    *(float4*)&out[(size_t)n * 64 + o] = make_float4(acc[o], acc[o + 1], acc[o + 2], acc[o + 3]);
}

// ---------------------------------------------------------------------------
// Fallback (ws too small): round-1 atomic scatter path
// ---------------------------------------------------------------------------
__global__ __launch_bounds__(256) void k_edge_at(
    const int* __restrict__ idx, const float* __restrict__ ef,
    const float* __restrict__ B, const float* __restrict__ c,
    const float* __restrict__ wm2, const float* __restrict__ bm2,
    const float* __restrict__ PRA, float* __restrict__ agg) {
  int e = blockIdx.x * 256 + threadIdx.x;
  if (e >= NE) return;
  int src = idx[e];
  int dst = idx[NE + e];
  float efr[32];
#pragma unroll
  for (int k = 0; k < 32; k += 4)
    *(float4*)&efr[k] = *(const float4*)&ef[(size_t)e * 32 + k];
  float m[64];
#pragma unroll
  for (int o = 0; o < 64; ++o) m[o] = bm2[o];
  const float* __restrict__ prs = &PRA[(size_t)src * 64];
#pragma unroll 1
  for (int jc = 0; jc < 64; jc += 16) {
    float q[16];
#pragma unroll
    for (int jj = 0; jj < 16; ++jj) q[jj] = c[jc + jj];
#pragma unroll
    for (int k = 0; k < 32; ++k) {
      float ev = efr[k];
#pragma unroll
      for (int jj = 0; jj < 16; ++jj) q[jj] += ev * B[k * 64 + jc + jj];
    }
#pragma unroll
    for (int jj = 0; jj < 16; ++jj) {
      float h = fmaxf(prs[jc + jj] + q[jj], 0.f);
#pragma unroll
      for (int o = 0; o < 64; ++o) m[o] += h * wm2[(jc + jj) * 64 + o];
    }
  }
  float* __restrict__ ap = &agg[(size_t)dst * 64];
#pragma unroll
  for (int o = 0; o < 64; ++o) atomicAdd(&ap[o], m[o]);
}

__global__ __launch_bounds__(256) void k_update_at(
    const float* __restrict__ agg, const float* __restrict__ PRU,
    const float* __restrict__ wu1, const float* __restrict__ bu1,
    const float* __restrict__ wu2, const float* __restrict__ bu2,
    float* __restrict__ out) {
  int n = blockIdx.x * 256 + threadIdx.x;
  if (n >= NN) return;
  float ar[64];
#pragma unroll
  for (int k = 0; k < 64; k += 4)
    *(float4*)&ar[k] = *(const float4*)&agg[(size_t)n * 64 + k];
  float acc[64];
#pragma unroll
  for (int o = 0; o < 64; ++o) acc[o] = bu2[o];
  const float* __restrict__ prs = &PRU[(size_t)n * 64];
#pragma unroll 1
  for (int jc = 0; jc < 64; jc += 16) {
    float q[16];
#pragma unroll
    for (int jj = 0; jj < 16; ++jj) q[jj] = bu1[jc + jj];
#pragma unroll
    for (int k = 0; k < 64; ++k) {
      float av = ar[k];
#pragma unroll
      for (int jj = 0; jj < 16; ++jj) q[jj] += av * wu1[(128 + k) * 64 + jc + jj];
    }
#pragma unroll
    for (int jj = 0; jj < 16; ++jj) {
      float h = fmaxf(prs[jc + jj] + q[jj], 0.f);
#pragma unroll
      for (int o = 0; o < 64; ++o) acc[o] += h * wu2[(jc + jj) * 64 + o];
    }
  }
#pragma unroll
  for (int o = 0; o < 64; o += 4)
    *(float4*)&out[(size_t)n * 64 + o] = make_float4(acc[o], acc[o + 1], acc[o + 2], acc[o + 3]);
}

extern "C" void kernel_launch(void* const* d_in, const int* in_sizes, int n_in,
                              void* d_out, int out_size, void* d_ws, size_t ws_size,
                              hipStream_t stream) {
  const float* nf  = (const float*)d_in[0];
  const int*   idx = (const int*)d_in[1];
  const float* ef  = (const float*)d_in[2];
  const float* wn  = (const float*)d_in[3];
  const float* bn  = (const float*)d_in[4];
  const float* we  = (const float*)d_in[5];
  const float* be  = (const float*)d_in[6];
  const float* wm1 = (const float*)d_in[7];
  const float* bm1 = (const float*)d_in[8];
  const float* wm2 = (const float*)d_in[9];
  const float* bm2 = (const float*)d_in[10];
  const float* wu1 = (const float*)d_in[11];
  const float* bu1 = (const float*)d_in[12];
  const float* wu2 = (const float*)d_in[13];
  const float* bu2 = (const float*)d_in[14];
  float* out = (float*)d_out;

  float* ws   = (float*)d_ws;
  float* M    = ws + OFF_M;
  float* B    = ws + OFF_B;
  float* c    = ws + OFF_C;
  float* W2U  = ws + OFF_W2U;
  float* d2   = ws + OFF_D2;
  int*   bsum = (int*)(ws + OFF_BSUM);
  int*   boff = (int*)(ws + OFF_BOFF);
  float* PRA  = ws + OFF_PRA;
  float* PRU  = ws + OFF_PRU;
  float* H    = ws + OFF_H;
  int*   hist = (int*)(ws + OFF_HIST);
  int*   cur  = (int*)(ws + OFF_CUR);
  int*   strt = (int*)(ws + OFF_STRT);
  int*   srcS = (int*)(ws + OFF_SRCS);
  unsigned short* qS = (unsigned short*)(ws + OFF_QS);

  const int SCAN_BLOCKS = (NN + 1023) / 1024;  // 98

  k_fold<<<(16384 + 2048 + 64 + 4096 + 64 + 255) / 256, 256, 0, stream>>>(
      wn, bn, we, be, wm1, bm1, wm2, bm2, wu1, M, B, c, W2U, d2);
  k_node<<<(NN + 255) / 256, 256, 0, stream>>>(nf, M, PRA, PRU);

  if (ws_size >= (size_t)WS_UNITS * 4) {
    hipMemsetAsync(hist, 0, (size_t)2 * NN * sizeof(int), stream);
    k_hist<<<(NE + 255) / 256, 256, 0, stream>>>(idx, hist);
    k_scanA<<<SCAN_BLOCKS, 1024, 0, stream>>>(hist, strt, bsum);
    k_scanB<<<1, 128, 0, stream>>>(bsum, boff, strt, SCAN_BLOCKS);
    k_scanC<<<SCAN_BLOCKS, 1024, 0, stream>>>(strt, boff);
    k_msgq2<<<(NE + 255) / 256, 256, 0, stream>>>(idx, strt, cur, ef, B, c, srcS, qS);
    k_gather7<<<(NN + 3) / 4, 256, 0, stream>>>(srcS, qS, strt, PRA, H);
    k_update3<<<(NN + 255) / 256, 256, 0, stream>>>(
        H, strt, PRU, W2U, d2, bu1, wu2, bu2, out);
  } else {
    hipMemsetAsync(H, 0, (size_t)NN * 64 * sizeof(float), stream);
    k_edge_at<<<(NE + 255) / 256, 256, 0, stream>>>(idx, ef, B, c, wm2, bm2, PRA, H);
    k_update_at<<<(NN + 255) / 256, 256, 0, stream>>>(
        H, PRU, wu1, bu1, wu2, bu2, out);
  }
}